// Round 6
// baseline (637.024 us; speedup 1.0000x reference)
//
#include <hip/hip_runtime.h>
#include <hip/hip_bf16.h>

typedef __bf16 bf16_t;
typedef __bf16 bf16x8 __attribute__((ext_vector_type(8)));
typedef __bf16 bf16x4 __attribute__((ext_vector_type(4)));
typedef __bf16 bf16x2 __attribute__((ext_vector_type(2)));
typedef float f32x4 __attribute__((ext_vector_type(4)));

#define MFMA16(a,b,c) __builtin_amdgcn_mfma_f32_16x16x32_bf16((a),(b),(c),0,0,0)
#define AS3(p) ((__attribute__((address_space(3))) void*)(p))
#define AS1(p) ((const __attribute__((address_space(1))) void*)(p))

constexpr int B_ = 4, L_ = 2048, E_ = 2048, H_ = 16, HD_ = 128;
constexpr size_t QK_ELEMS = (size_t)B_ * H_ * L_ * HD_;    // 16,777,216
constexpr size_t NX = (size_t)B_ * L_ * E_;                // 16,777,216
constexpr size_t NW = (size_t)3 * E_ * E_;                 // 12,582,912

// ---------------------------------------------------------------------------
// Kernel 0: fp32 -> bf16 conversion of X and W into one contiguous dst
// (dst lives in d_out's first 58.7MB; overwritten later by attn's output).
// ---------------------------------------------------------------------------
__global__ __launch_bounds__(256) void cvt(
    const float* __restrict__ X, const float* __restrict__ W, bf16_t* __restrict__ dst)
{
  size_t e = ((size_t)blockIdx.x * 256 + threadIdx.x) * 4;
  f32x4 v = (e < NX) ? *(const f32x4*)&X[e] : *(const f32x4*)&W[e - NX];
  bf16x4 o;
  for (int u = 0; u < 4; ++u) o[u] = (__bf16)v[u];
  *(bf16x4*)&dst[e] = o;
}

// ---------------------------------------------------------------------------
// Kernel 1: y = Xb @ Wb^T + b, fused with F.normalize for q/k.
// 256x256 tile, BK=64, 8 waves (2Mx4N), 512 threads — the m201 8-phase
// template geometry, adapted: 4 phases/K-tile, counted vmcnt(8) (never 0
// in-loop), raw s_barrier (NOT __syncthreads: that re-inserts the vmcnt(0)
// drain = the m97 stall), setprio around MFMA clusters (T5, pays only on
// this phase-split structure per m218b).
//   - LDS swizzle (T2): chunk ^= (row&7) WITHIN each 128B row. r3's lesson:
//     the source permutation must stay inside a cache line or staging
//     coalescing dies (+130us). XOR within 128B keeps stage coalesced AND
//     makes the stride-128B fragment reads <=2-way (free, m136).
//     Linear gload_lds dest + inverse-permuted source + swizzled read
//     (rule #21; XOR is its own inverse).
//   - Double-buffered K-tiles; stage(t+2) issued after the barrier ending
//     tile t's reads (same buffer, vacated); vmcnt(8)+barrier then proves
//     tile t+1 landed in all waves.
// LDS: 2*32KB A + 2*32KB B = 128KB -> 1 block/CU, 2 waves/SIMD.
// Epilogue: bias + fused L2-norm for q/k chunks (which = wave-uniform),
// scatter q,k -> [B,H,L,HD], v -> vT [B,H,HD,L] (bf16).
// ---------------------------------------------------------------------------
constexpr int BM = 256, BN = 256, BK = 64, KTILES = E_ / BK;  // 32

__global__ __launch_bounds__(512, 2) void gemm_qkv(
    const bf16_t* __restrict__ Xb, const bf16_t* __restrict__ Wb, const float* __restrict__ bias,
    bf16_t* __restrict__ q, bf16_t* __restrict__ k, bf16_t* __restrict__ vT)
{
  __shared__ alignas(16) bf16_t Al[2][BM * BK];   // 2 x 32KB
  __shared__ alignas(16) bf16_t Bl[2][BN * BK];   // 2 x 32KB
  const int tid = threadIdx.x;
  const int wave = tid >> 6, lane = tid & 63;
  const int wm = wave >> 2, wn = wave & 3;

  // XCD-aware bijective swizzle (768 blocks, 768%8==0 -> simple form valid)
  const int bid = blockIdx.y * 24 + blockIdx.x;
  const int swz = (bid & 7) * 96 + (bid >> 3);
  const int bx = swz % 24, by = swz / 24;
  const int m0 = by * BM, n0 = bx * BN;

  // ---- staging: lane j covers (row_local = j>>3, dest chunk-slot = j&7);
  // slot c' holds global chunk c = c' ^ (row&7). gload_lds writes linearly.
  const int r8 = lane >> 3;
  const int cSrc = (lane & 7) ^ r8;
  const bf16_t* gA = &Xb[(size_t)(m0 + wave * 8 + r8) * E_ + cSrc * 8];
  const bf16_t* gB = &Wb[(size_t)(n0 + wave * 8 + r8) * E_ + cSrc * 8];

#define STAGE(buf, t) do { \
    const bf16_t* sa_ = gA + (t) * BK; \
    const bf16_t* sb_ = gB + (t) * BK; \
    bf16_t* la_ = &Al[buf][wave * 512]; \
    bf16_t* lb_ = &Bl[buf][wave * 512]; \
    __builtin_amdgcn_global_load_lds(AS1(sa_),                       AS3(la_),         16, 0, 0); \
    __builtin_amdgcn_global_load_lds(AS1(sa_ + (size_t)64 * E_),     AS3(la_ +  4096), 16, 0, 0); \
    __builtin_amdgcn_global_load_lds(AS1(sa_ + (size_t)128 * E_),    AS3(la_ +  8192), 16, 0, 0); \
    __builtin_amdgcn_global_load_lds(AS1(sa_ + (size_t)192 * E_),    AS3(la_ + 12288), 16, 0, 0); \
    __builtin_amdgcn_global_load_lds(AS1(sb_),                       AS3(lb_),         16, 0, 0); \
    __builtin_amdgcn_global_load_lds(AS1(sb_ + (size_t)64 * E_),     AS3(lb_ +  4096), 16, 0, 0); \
    __builtin_amdgcn_global_load_lds(AS1(sb_ + (size_t)128 * E_),    AS3(lb_ +  8192), 16, 0, 0); \
    __builtin_amdgcn_global_load_lds(AS1(sb_ + (size_t)192 * E_),    AS3(lb_ + 12288), 16, 0, 0); \
  } while (0)

  // ---- fragment reads (swizzled): row R, k-chunk (ks*4+q4) ^ (R&7)
  const int rowf = lane & 15, q4 = lane >> 4, rkey = lane & 7;
#define RD_A(buf, mtg, ks) (*(const bf16x8*)&Al[buf][(wm * 128 + (mtg) * 16 + rowf) * 64 + ((((ks) << 2) | q4) ^ rkey) * 8])
#define RD_B(buf, nt, ks)  (*(const bf16x8*)&Bl[buf][(wn * 64  + (nt) * 16 + rowf) * 64 + ((((ks) << 2) | q4) ^ rkey) * 8])
#define SBAR() __builtin_amdgcn_s_barrier()

  const f32x4 fzero = {0.f, 0.f, 0.f, 0.f};
  f32x4 acc[8][4];
#pragma unroll
  for (int i = 0; i < 8; ++i)
#pragma unroll
    for (int j = 0; j < 4; ++j) acc[i][j] = fzero;

  STAGE(0, 0);
  STAGE(1, 1);
  asm volatile("s_waitcnt vmcnt(8)" ::: "memory");   // tile 0 landed (8 of tile 1 may fly)
  SBAR();

  for (int t = 0; t < KTILES; ++t) {
    const int cur = t & 1;
    bf16x8 bfr[4][2];
#pragma unroll
    for (int p = 0; p < 4; ++p) {
      bf16x8 af[2][2];
#pragma unroll
      for (int i = 0; i < 2; ++i)
#pragma unroll
        for (int ks = 0; ks < 2; ++ks)
          af[i][ks] = RD_A(cur, p * 2 + i, ks);
      if (p == 0) {
#pragma unroll
        for (int nt = 0; nt < 4; ++nt)
#pragma unroll
          for (int ks = 0; ks < 2; ++ks)
            bfr[nt][ks] = RD_B(cur, nt, ks);
      }
      SBAR();
      __builtin_amdgcn_s_setprio(1);
#pragma unroll
      for (int i = 0; i < 2; ++i)
#pragma unroll
        for (int nt = 0; nt < 4; ++nt)
#pragma unroll
          for (int ks = 0; ks < 2; ++ks)
            acc[p * 2 + i][nt] = MFMA16(af[i][ks], bfr[nt][ks], acc[p * 2 + i][nt]);
      __builtin_amdgcn_s_setprio(0);
      if (p < 3) SBAR();
    }
    // tile boundary: reads of buf[cur] provably done -> restage it
    asm volatile("s_waitcnt lgkmcnt(0)" ::: "memory");
    SBAR();
    if (t + 2 < KTILES) {
      STAGE(cur, t + 2);
      asm volatile("s_waitcnt vmcnt(8)" ::: "memory"); // tile t+1's 8 loads landed
    } else {
      asm volatile("s_waitcnt vmcnt(0)" ::: "memory");
    }
    SBAR();
  }
#undef STAGE
#undef RD_A
#undef RD_B

  __syncthreads();   // one full drain before LDS reuse (epilogue only)

  const int b  = m0 >> 11;
  const int l0 = m0 & (L_ - 1);
  const int gch = 2 * bx + (wn >> 1);      // global 128-col chunk, wave-uniform
  const int h   = gch / 3;
  const int which = gch % 3;               // 0=q 1=k 2=v, wave-uniform
  const int rlane = (lane >> 4) << 2;      // C/D row base = (lane>>4)*4
  const int clane = lane & 15;             // C/D col = lane&15

  float bcol[4];
#pragma unroll
  for (int nt = 0; nt < 4; ++nt)
    bcol[nt] = bias[n0 + wn * 64 + nt * 16 + clane];
#pragma unroll
  for (int mt = 0; mt < 8; ++mt)
#pragma unroll
    for (int nt = 0; nt < 4; ++nt)
#pragma unroll
      for (int r = 0; r < 4; ++r)
        acc[mt][nt][r] += bcol[nt];

  // fused L2 norm: cross-wave (wn pair) sum-of-squares exchange.
  float* NormS = (float*)&Al[0][0];   // [2 chunks][256 rows][2 halves] = 4KB
  if (which < 2) {
#pragma unroll
    for (int mt = 0; mt < 8; ++mt)
#pragma unroll
      for (int r = 0; r < 4; ++r) {
        float sq = 0.f;
#pragma unroll
        for (int nt = 0; nt < 4; ++nt) sq += acc[mt][nt][r] * acc[mt][nt][r];
#pragma unroll
        for (int off = 8; off; off >>= 1) sq += __shfl_xor(sq, off);  // 16-lane row group
        if (clane == 0) {
          int row = wm * 128 + mt * 16 + rlane + r;
          NormS[((wn >> 1) * 256 + row) * 2 + (wn & 1)] = sq;
        }
      }
  }
  __syncthreads();   // unconditional (which differs across waves)

  if (which < 2) {
    bf16_t* base = ((which == 0) ? q : k) + ((size_t)(b * H_ + h) * L_) * HD_;
#pragma unroll
    for (int mt = 0; mt < 8; ++mt)
#pragma unroll
      for (int r = 0; r < 4; ++r) {
        int row = wm * 128 + mt * 16 + rlane + r;
        float tot = NormS[((wn >> 1) * 256 + row) * 2] + NormS[((wn >> 1) * 256 + row) * 2 + 1];
        float invn = 1.0f / fmaxf(sqrtf(tot), 1e-12f);   // matches F.normalize eps
        bf16_t* rowp = base + (size_t)(l0 + row) * HD_;
#pragma unroll
        for (int nt = 0; nt < 4; ++nt) {
          int hd = (wn & 1) * 64 + nt * 16 + clane;
          rowp[hd] = (__bf16)(acc[mt][nt][r] * invn);
        }
      }
  } else {
    bf16_t* base = vT + ((size_t)(b * H_ + h) * HD_) * L_;
#pragma unroll
    for (int mt = 0; mt < 8; ++mt)
#pragma unroll
      for (int r = 0; r < 4; ++r) {
        int l = l0 + wm * 128 + mt * 16 + rlane + r;
#pragma unroll
        for (int nt = 0; nt < 4; ++nt) {
          int hd = (wn & 1) * 64 + nt * 16 + clane;
          base[(size_t)hd * L_ + l] = (__bf16)acc[mt][nt][r];
        }
      }
  }
}

// ---------------------------------------------------------------------------
// Kernel 3: flash-style attention (verified in round 1; unchanged).
//   - cosine scores (|S|<=1) => softmax-lite: p=exp(s), denom reduced once.
//   - Q fragments in registers; private P buffer; 2 barriers/iter.
//   - T14 async staging; T5 setprio.
// LDS: Ks 16KB + Vts 16KB + Ps 16KB = 48KB. Output fp32 [B,L,H,HD].
// ---------------------------------------------------------------------------
__device__ __forceinline__ int swz128(int r, int c) {
  return r * 128 + ((((c >> 3) ^ (r & 15)) & 15) << 3) + (c & 7);
}
__device__ __forceinline__ int swz64(int r, int c) {
  return r * 64 + ((((c >> 3) ^ (r & 7)) & 7) << 3) + (c & 7);
}

__global__ __launch_bounds__(256) void attn(
    const bf16_t* __restrict__ q, const bf16_t* __restrict__ k,
    const bf16_t* __restrict__ vT, float* __restrict__ out)
{
  __shared__ alignas(16) bf16_t Ks[64 * 128];   // [j][d], swizzled
  __shared__ alignas(16) bf16_t Vts[128 * 64];  // [d][j], swizzled
  __shared__ alignas(16) bf16_t Ps[128 * 64];   // [l][j], swizzled (own-wave rows)

  const int tid = threadIdx.x, wave = tid >> 6, lane = tid & 63;
  const int bh = blockIdx.y;
  const int q0 = blockIdx.x * 128;
  const int rowf = lane & 15, kq8 = (lane >> 4) * 8;

  const bf16_t* qbase = q + ((size_t)bh * L_ + q0) * HD_;
  const bf16_t* kbh = k + (size_t)bh * L_ * HD_;
  const bf16_t* vbh = vT + (size_t)bh * HD_ * L_;

  // Q fragments: loop-invariant, straight from global (one-time, L2-served)
  bf16x8 qf[4][2];
  for (int kk4 = 0; kk4 < 4; ++kk4)
    for (int mt = 0; mt < 2; ++mt)
      qf[kk4][mt] = *(const bf16x8*)&qbase[(size_t)(wave * 32 + mt * 16 + rowf) * HD_ + kk4 * 32 + kq8];

  const f32x4 fzero = {0.f, 0.f, 0.f, 0.f};
  f32x4 o[2][8];
  for (int mt = 0; mt < 2; ++mt)
    for (int nt = 0; nt < 8; ++nt) o[mt][nt] = fzero;
  float lrow[2][4];
  for (int mt = 0; mt < 2; ++mt)
    for (int r = 0; r < 4; ++r) lrow[mt][r] = 0.f;

  // staging registers (async prefetch)
  bf16x8 kreg[4], vreg[4];

  // ---- prologue: tile 0 load + store ----
  for (int i = 0; i < 4; ++i) {
    int e = (i * 256 + tid) * 8;
    kreg[i] = *(const bf16x8*)&kbh[e];
  }
  for (int i = 0; i < 4; ++i) {
    int e = (i * 256 + tid) * 8;
    int d = e >> 6, c = e & 63;
    vreg[i] = *(const bf16x8*)&vbh[(size_t)d * L_ + c];
  }
  for (int i = 0; i < 4; ++i) {
    int e = (i * 256 + tid) * 8;
    *(bf16x8*)&Ks[swz128(e >> 7, e & 127)] = kreg[i];
  }
  for (int i = 0; i < 4; ++i) {
    int e = (i * 256 + tid) * 8;
    int d = e >> 6, c = e & 63;
    *(bf16x8*)&Vts[swz64(d, c)] = vreg[i];
  }
  __syncthreads();

  for (int j0 = 0; j0 < L_; j0 += 64) {
    const bool more = (j0 + 64 < L_);
    // issue next tile's loads now; latency hides under QK^T + softmax + PV
    if (more) {
      const int jn = j0 + 64;
      for (int i = 0; i < 4; ++i) {
        int e = (i * 256 + tid) * 8;
        kreg[i] = *(const bf16x8*)&kbh[(size_t)jn * HD_ + e];
      }
      for (int i = 0; i < 4; ++i) {
        int e = (i * 256 + tid) * 8;
        int d = e >> 6, c = e & 63;
        vreg[i] = *(const bf16x8*)&vbh[(size_t)d * L_ + jn + c];
      }
    }

    // S = Q K^T
    f32x4 s[2][4];
    for (int mt = 0; mt < 2; ++mt)
      for (int nt = 0; nt < 4; ++nt) s[mt][nt] = fzero;
    __builtin_amdgcn_s_setprio(1);
    for (int kk = 0; kk < 128; kk += 32) {
      bf16x8 bk4[4];
      for (int nt = 0; nt < 4; ++nt) bk4[nt] = *(const bf16x8*)&Ks[swz128(nt * 16 + rowf, kk + kq8)];
      for (int mt = 0; mt < 2; ++mt)
        for (int nt = 0; nt < 4; ++nt)
          s[mt][nt] = MFMA16(qf[kk >> 5][mt], bk4[nt], s[mt][nt]);
    }
    __builtin_amdgcn_s_setprio(0);

    // softmax-lite: |s| <= 1, so p = exp(s) is unconditionally stable.
    for (int mt = 0; mt < 2; ++mt)
      for (int nt = 0; nt < 4; ++nt)
        for (int r = 0; r < 4; ++r) {
          float p = __expf(s[mt][nt][r]);
          lrow[mt][r] += p;
          int rr = wave * 32 + mt * 16 + ((lane >> 4) << 2) + r;
          int cc = nt * 16 + (lane & 15);
          Ps[swz64(rr, cc)] = (__bf16)p;
        }

    // O += P @ V   (P rows are own-wave only: intra-wave lgkmcnt ordering)
    __builtin_amdgcn_s_setprio(1);
    for (int kk = 0; kk < 64; kk += 32) {
      bf16x8 ap[2];
      for (int mt = 0; mt < 2; ++mt)
        ap[mt] = *(const bf16x8*)&Ps[swz64(wave * 32 + mt * 16 + rowf, kk + kq8)];
      for (int nt = 0; nt < 8; ++nt) {
        bf16x8 bvv = *(const bf16x8*)&Vts[swz64(nt * 16 + rowf, kk + kq8)];
        for (int mt = 0; mt < 2; ++mt)
          o[mt][nt] = MFMA16(ap[mt], bvv, o[mt][nt]);
      }
    }
    __builtin_amdgcn_s_setprio(0);

    __syncthreads();          // all waves done reading Ks/Vts
    if (more) {
      for (int i = 0; i < 4; ++i) {
        int e = (i * 256 + tid) * 8;
        *(bf16x8*)&Ks[swz128(e >> 7, e & 127)] = kreg[i];
      }
      for (int i = 0; i < 4; ++i) {
        int e = (i * 256 + tid) * 8;
        int d = e >> 6, c = e & 63;
        *(bf16x8*)&Vts[swz64(d, c)] = vreg[i];
      }
      __syncthreads();
    }
  }

  // epilogue: single denom reduce, divide, write fp32 out [B][L][H][HD]
  const int b = bh >> 4, h = bh & 15;
  for (int mt = 0; mt < 2; ++mt) {
    for (int r = 0; r < 4; ++r) {
      float lsum = lrow[mt][r];
      for (int off = 8; off; off >>= 1) lsum += __shfl_xor(lsum, off);
      float inv = 1.0f / lsum;
      int l = q0 + wave * 32 + mt * 16 + ((lane >> 4) << 2) + r;
      float* op = out + (((size_t)b * L_ + l) * H_ + h) * HD_;
      for (int nt = 0; nt < 8; ++nt) {
        int d = nt * 16 + (lane & 15);
        op[d] = o[mt][nt][r] * inv;
      }
    }
  }
}

// ---------------------------------------------------------------------------
extern "C" void kernel_launch(void* const* d_in, const int* in_sizes, int n_in,
                              void* d_out, int out_size, void* d_ws, size_t ws_size,
                              hipStream_t stream)
{
  const float* X    = (const float*)d_in[0];   // [4,2048,2048] fp32
  const float* W    = (const float*)d_in[1];   // [6144,2048] fp32
  const float* bias = (const float*)d_in[2];   // [6144] fp32
  float* out = (float*)d_out;                  // [4,2048,2048] fp32

  // bf16 copies of X and W live inside d_out (58.7MB < 67.1MB); d_out is not
  // written by anything until attn, which runs after gemm_qkv has consumed them.
  bf16_t* Xb = (bf16_t*)d_out;
  bf16_t* Wb = Xb + NX;

  bf16_t* q  = (bf16_t*)d_ws;                  // [B,H,L,HD] 32MB (L2-normalized)
  bf16_t* k  = q + QK_ELEMS;                   // 32MB (L2-normalized)
  bf16_t* vT = k + QK_ELEMS;                   // [B,H,HD,L] 32MB

  cvt<<<dim3((NX + NW) / (256 * 4)), 256, 0, stream>>>(X, W, Xb);
  gemm_qkv<<<dim3(24, 32), 512, 0, stream>>>(Xb, Wb, bias, q, k, vT);
  attn<<<dim3(16, 64), 256, 0, stream>>>(q, k, vT, out);
}

// Round 7
// 635.567 us; speedup vs baseline: 1.0023x; 1.0023x over previous
//
#include <hip/hip_runtime.h>
#include <hip/hip_bf16.h>

typedef __bf16 bf16_t;
typedef __bf16 bf16x8 __attribute__((ext_vector_type(8)));
typedef __bf16 bf16x4 __attribute__((ext_vector_type(4)));
typedef __bf16 bf16x2 __attribute__((ext_vector_type(2)));
typedef float f32x4 __attribute__((ext_vector_type(4)));

#define MFMA16(a,b,c) __builtin_amdgcn_mfma_f32_16x16x32_bf16((a),(b),(c),0,0,0)
#define AS3(p) ((__attribute__((address_space(3))) void*)(p))
#define AS1(p) ((const __attribute__((address_space(1))) void*)(p))

constexpr int B_ = 4, L_ = 2048, E_ = 2048, H_ = 16, HD_ = 128;
constexpr size_t QK_ELEMS = (size_t)B_ * H_ * L_ * HD_;    // 16,777,216
constexpr size_t NX = (size_t)B_ * L_ * E_;                // 16,777,216
constexpr size_t NW = (size_t)3 * E_ * E_;                 // 12,582,912

// ---------------------------------------------------------------------------
// Kernel 0: fp32 -> bf16 conversion of X and W into one contiguous dst
// (dst lives in d_out's first 58.7MB; overwritten later by attn's output).
// ---------------------------------------------------------------------------
__global__ __launch_bounds__(256) void cvt(
    const float* __restrict__ X, const float* __restrict__ W, bf16_t* __restrict__ dst)
{
  size_t e = ((size_t)blockIdx.x * 256 + threadIdx.x) * 4;
  f32x4 v = (e < NX) ? *(const f32x4*)&X[e] : *(const f32x4*)&W[e - NX];
  bf16x4 o;
  for (int u = 0; u < 4; ++u) o[u] = (__bf16)v[u];
  *(bf16x4*)&dst[e] = o;
}

// ---------------------------------------------------------------------------
// Kernel 1: y = Xb @ Wb^T + b, fused with F.normalize for q/k.
// 256x256 tile, BK=64, 8 waves (2Mx4N), 512 threads — m201 8-phase template:
// 4 phases/K-tile, counted vmcnt(8) (never 0 in-loop), raw s_barrier,
// setprio around MFMA (T5). In-row XOR swizzle (T2) with linear gload_lds
// dest + inverse-permuted source + swizzled read (rule #21).
// UNCHANGED from r6 (inferred ~165us there; this round makes it measurable).
// ---------------------------------------------------------------------------
constexpr int BM = 256, BN = 256, BK = 64, KTILES = E_ / BK;  // 32

__global__ __launch_bounds__(512, 2) void gemm_qkv(
    const bf16_t* __restrict__ Xb, const bf16_t* __restrict__ Wb, const float* __restrict__ bias,
    bf16_t* __restrict__ q, bf16_t* __restrict__ k, bf16_t* __restrict__ vT)
{
  __shared__ alignas(16) bf16_t Al[2][BM * BK];   // 2 x 32KB
  __shared__ alignas(16) bf16_t Bl[2][BN * BK];   // 2 x 32KB
  const int tid = threadIdx.x;
  const int wave = tid >> 6, lane = tid & 63;
  const int wm = wave >> 2, wn = wave & 3;

  // XCD-aware bijective swizzle (768 blocks, 768%8==0 -> simple form valid)
  const int bid = blockIdx.y * 24 + blockIdx.x;
  const int swz = (bid & 7) * 96 + (bid >> 3);
  const int bx = swz % 24, by = swz / 24;
  const int m0 = by * BM, n0 = bx * BN;

  // staging: lane j covers (row_local = j>>3, dest chunk-slot = j&7);
  // slot c' holds global chunk c = c' ^ (row&7). gload_lds writes linearly.
  const int r8 = lane >> 3;
  const int cSrc = (lane & 7) ^ r8;
  const bf16_t* gA = &Xb[(size_t)(m0 + wave * 8 + r8) * E_ + cSrc * 8];
  const bf16_t* gB = &Wb[(size_t)(n0 + wave * 8 + r8) * E_ + cSrc * 8];

#define STAGE(buf, t) do { \
    const bf16_t* sa_ = gA + (t) * BK; \
    const bf16_t* sb_ = gB + (t) * BK; \
    bf16_t* la_ = &Al[buf][wave * 512]; \
    bf16_t* lb_ = &Bl[buf][wave * 512]; \
    __builtin_amdgcn_global_load_lds(AS1(sa_),                       AS3(la_),         16, 0, 0); \
    __builtin_amdgcn_global_load_lds(AS1(sa_ + (size_t)64 * E_),     AS3(la_ +  4096), 16, 0, 0); \
    __builtin_amdgcn_global_load_lds(AS1(sa_ + (size_t)128 * E_),    AS3(la_ +  8192), 16, 0, 0); \
    __builtin_amdgcn_global_load_lds(AS1(sa_ + (size_t)192 * E_),    AS3(la_ + 12288), 16, 0, 0); \
    __builtin_amdgcn_global_load_lds(AS1(sb_),                       AS3(lb_),         16, 0, 0); \
    __builtin_amdgcn_global_load_lds(AS1(sb_ + (size_t)64 * E_),     AS3(lb_ +  4096), 16, 0, 0); \
    __builtin_amdgcn_global_load_lds(AS1(sb_ + (size_t)128 * E_),    AS3(lb_ +  8192), 16, 0, 0); \
    __builtin_amdgcn_global_load_lds(AS1(sb_ + (size_t)192 * E_),    AS3(lb_ + 12288), 16, 0, 0); \
  } while (0)

  // fragment reads (swizzled): row R, k-chunk (ks*4+q4) ^ (R&7)
  const int rowf = lane & 15, q4 = lane >> 4, rkey = lane & 7;
#define RD_A(buf, mtg, ks) (*(const bf16x8*)&Al[buf][(wm * 128 + (mtg) * 16 + rowf) * 64 + ((((ks) << 2) | q4) ^ rkey) * 8])
#define RD_B(buf, nt, ks)  (*(const bf16x8*)&Bl[buf][(wn * 64  + (nt) * 16 + rowf) * 64 + ((((ks) << 2) | q4) ^ rkey) * 8])
#define SBAR() __builtin_amdgcn_s_barrier()

  const f32x4 fzero = {0.f, 0.f, 0.f, 0.f};
  f32x4 acc[8][4];
#pragma unroll
  for (int i = 0; i < 8; ++i)
#pragma unroll
    for (int j = 0; j < 4; ++j) acc[i][j] = fzero;

  STAGE(0, 0);
  STAGE(1, 1);
  asm volatile("s_waitcnt vmcnt(8)" ::: "memory");   // tile 0 landed (8 of tile 1 may fly)
  SBAR();

  for (int t = 0; t < KTILES; ++t) {
    const int cur = t & 1;
    bf16x8 bfr[4][2];
#pragma unroll
    for (int p = 0; p < 4; ++p) {
      bf16x8 af[2][2];
#pragma unroll
      for (int i = 0; i < 2; ++i)
#pragma unroll
        for (int ks = 0; ks < 2; ++ks)
          af[i][ks] = RD_A(cur, p * 2 + i, ks);
      if (p == 0) {
#pragma unroll
        for (int nt = 0; nt < 4; ++nt)
#pragma unroll
          for (int ks = 0; ks < 2; ++ks)
            bfr[nt][ks] = RD_B(cur, nt, ks);
      }
      SBAR();
      __builtin_amdgcn_s_setprio(1);
#pragma unroll
      for (int i = 0; i < 2; ++i)
#pragma unroll
        for (int nt = 0; nt < 4; ++nt)
#pragma unroll
          for (int ks = 0; ks < 2; ++ks)
            acc[p * 2 + i][nt] = MFMA16(af[i][ks], bfr[nt][ks], acc[p * 2 + i][nt]);
      __builtin_amdgcn_s_setprio(0);
      if (p < 3) SBAR();
    }
    // tile boundary: reads of buf[cur] provably done -> restage it
    asm volatile("s_waitcnt lgkmcnt(0)" ::: "memory");
    SBAR();
    if (t + 2 < KTILES) {
      STAGE(cur, t + 2);
      asm volatile("s_waitcnt vmcnt(8)" ::: "memory"); // tile t+1's 8 loads landed
    } else {
      asm volatile("s_waitcnt vmcnt(0)" ::: "memory");
    }
    SBAR();
  }
#undef STAGE
#undef RD_A
#undef RD_B

  __syncthreads();   // one full drain before LDS reuse (epilogue only)

  const int b  = m0 >> 11;
  const int l0 = m0 & (L_ - 1);
  const int gch = 2 * bx + (wn >> 1);      // global 128-col chunk, wave-uniform
  const int h   = gch / 3;
  const int which = gch % 3;               // 0=q 1=k 2=v, wave-uniform
  const int rlane = (lane >> 4) << 2;      // C/D row base = (lane>>4)*4
  const int clane = lane & 15;             // C/D col = lane&15

  float bcol[4];
#pragma unroll
  for (int nt = 0; nt < 4; ++nt)
    bcol[nt] = bias[n0 + wn * 64 + nt * 16 + clane];
#pragma unroll
  for (int mt = 0; mt < 8; ++mt)
#pragma unroll
    for (int nt = 0; nt < 4; ++nt)
#pragma unroll
      for (int r = 0; r < 4; ++r)
        acc[mt][nt][r] += bcol[nt];

  // fused L2 norm: cross-wave (wn pair) sum-of-squares exchange.
  float* NormS = (float*)&Al[0][0];   // [2 chunks][256 rows][2 halves] = 4KB
  if (which < 2) {
#pragma unroll
    for (int mt = 0; mt < 8; ++mt)
#pragma unroll
      for (int r = 0; r < 4; ++r) {
        float sq = 0.f;
#pragma unroll
        for (int nt = 0; nt < 4; ++nt) sq += acc[mt][nt][r] * acc[mt][nt][r];
#pragma unroll
        for (int off = 8; off; off >>= 1) sq += __shfl_xor(sq, off);  // 16-lane row group
        if (clane == 0) {
          int row = wm * 128 + mt * 16 + rlane + r;
          NormS[((wn >> 1) * 256 + row) * 2 + (wn & 1)] = sq;
        }
      }
  }
  __syncthreads();   // unconditional (which differs across waves)

  if (which < 2) {
    bf16_t* base = ((which == 0) ? q : k) + ((size_t)(b * H_ + h) * L_) * HD_;
#pragma unroll
    for (int mt = 0; mt < 8; ++mt)
#pragma unroll
      for (int r = 0; r < 4; ++r) {
        int row = wm * 128 + mt * 16 + rlane + r;
        float tot = NormS[((wn >> 1) * 256 + row) * 2] + NormS[((wn >> 1) * 256 + row) * 2 + 1];
        float invn = 1.0f / fmaxf(sqrtf(tot), 1e-12f);   // matches F.normalize eps
        bf16_t* rowp = base + (size_t)(l0 + row) * HD_;
#pragma unroll
        for (int nt = 0; nt < 4; ++nt) {
          int hd = (wn & 1) * 64 + nt * 16 + clane;
          rowp[hd] = (__bf16)(acc[mt][nt][r] * invn);
        }
      }
  } else {
    bf16_t* base = vT + ((size_t)(b * H_ + h) * HD_) * L_;
#pragma unroll
    for (int mt = 0; mt < 8; ++mt)
#pragma unroll
      for (int r = 0; r < 4; ++r) {
        int l = l0 + wm * 128 + mt * 16 + rlane + r;
#pragma unroll
        for (int nt = 0; nt < 4; ++nt) {
          int hd = (wn & 1) * 64 + nt * 16 + clane;
          base[(size_t)hd * L_ + l] = (__bf16)acc[mt][nt][r];
        }
      }
  }
}

// ---------------------------------------------------------------------------
// Kernel 3: flash-style attention, staging made STRUCTURAL (r6 lesson:
// reg-staged T14 pipeline was compiler-discretionary — co-compile context
// change sank the prefetch loads, 164->279us with identical source).
//   - K/V staged via double-buffered global_load_lds (HW DMA, can't be
//     scheduled away). Swizzle kept by pre-permuting the per-lane global
//     source WITHIN each row (rule #21; r3 lesson: in-row only) while
//     gload_lds writes linearly. Read side: swz128/swz64 unchanged.
//   - ONE __syncthreads per tile (was 2): stage(next) issued at iter top,
//     full tile of compute covers flight; barrier's vmcnt(0) drain ~free.
//   - XCD bh-grouping swizzle (T1): all 16 q-tiles of a head on one XCD
//     -> K/V L2-resident per XCD.
//   - cosine scores (|S|<=1) => softmax-lite (r1-proven exact).
// LDS: Ks 2x16KB + Vts 2x16KB + Ps 16KB = 80KB -> 2 blocks/CU.
// Output fp32 [B,L,H,HD].
// ---------------------------------------------------------------------------
__device__ __forceinline__ int swz128(int r, int c) {
  return r * 128 + ((((c >> 3) ^ (r & 15)) & 15) << 3) + (c & 7);
}
__device__ __forceinline__ int swz64(int r, int c) {
  return r * 64 + ((((c >> 3) ^ (r & 7)) & 7) << 3) + (c & 7);
}

__global__ __launch_bounds__(256) void attn(
    const bf16_t* __restrict__ q, const bf16_t* __restrict__ k,
    const bf16_t* __restrict__ vT, float* __restrict__ out)
{
  __shared__ alignas(16) bf16_t Ks[2][64 * 128];   // [j][d], swizzled content
  __shared__ alignas(16) bf16_t Vts[2][128 * 64];  // [d][j], swizzled content
  __shared__ alignas(16) bf16_t Ps[128 * 64];      // [l][j], swizzled (own-wave rows)

  const int tid = threadIdx.x, wave = tid >> 6, lane = tid & 63;

  // XCD bh-grouping: contiguous virtual ids per XCD -> q-tiles of one head
  // share an XCD's L2. 1024 blocks, 1024%8==0 -> bijective.
  const int sid = blockIdx.y * 16 + blockIdx.x;
  const int vid = (sid & 7) * 128 + (sid >> 3);
  const int bh = vid >> 4;
  const int q0 = (vid & 15) << 7;

  const int rowf = lane & 15, kq8 = (lane >> 4) * 8;

  const bf16_t* qbase = q + ((size_t)bh * L_ + q0) * HD_;
  const bf16_t* kbh = k + (size_t)bh * L_ * HD_;
  const bf16_t* vbh = vT + (size_t)bh * HD_ * L_;

  // staging: per inst, wave covers 4 K-rows (16 slots each) / 8 V-rows
  // (8 slots each); slot s of row r holds global chunk s ^ (r & key).
  // LDS dest = uniform base + lane*16B (linear); source pre-permuted in-row.
#define STAGE_KV(buf, j0v) do { \
    for (int i_ = 0; i_ < 4; ++i_) { \
      int r_ = i_ * 16 + wave * 4 + (lane >> 4); \
      int c_ = (lane & 15) ^ (r_ & 15); \
      __builtin_amdgcn_global_load_lds(AS1(kbh + (size_t)((j0v) + r_) * HD_ + c_ * 8), \
                                       AS3(&Ks[buf][i_ * 2048 + wave * 512]), 16, 0, 0); \
    } \
    for (int i_ = 0; i_ < 4; ++i_) { \
      int d_ = i_ * 32 + wave * 8 + (lane >> 3); \
      int c_ = (lane & 7) ^ (d_ & 7); \
      __builtin_amdgcn_global_load_lds(AS1(vbh + (size_t)d_ * L_ + (j0v) + c_ * 8), \
                                       AS3(&Vts[buf][i_ * 2048 + wave * 512]), 16, 0, 0); \
    } \
  } while (0)

  // Q fragments: loop-invariant, straight from global (one-time, L2-served)
  bf16x8 qf[4][2];
  for (int kk4 = 0; kk4 < 4; ++kk4)
    for (int mt = 0; mt < 2; ++mt)
      qf[kk4][mt] = *(const bf16x8*)&qbase[(size_t)(wave * 32 + mt * 16 + rowf) * HD_ + kk4 * 32 + kq8];

  const f32x4 fzero = {0.f, 0.f, 0.f, 0.f};
  f32x4 o[2][8];
  for (int mt = 0; mt < 2; ++mt)
    for (int nt = 0; nt < 8; ++nt) o[mt][nt] = fzero;
  float lrow[2][4];
  for (int mt = 0; mt < 2; ++mt)
    for (int r = 0; r < 4; ++r) lrow[mt][r] = 0.f;

  STAGE_KV(0, 0);
  __syncthreads();          // tile 0 landed (vmcnt(0) drain in barrier)
  int cur = 0;

  for (int j0 = 0; j0 < L_; j0 += 64) {
    if (j0 + 64 < L_) STAGE_KV(cur ^ 1, j0 + 64);  // flies over this tile's compute

    // S = Q K^T
    f32x4 s[2][4];
    for (int mt = 0; mt < 2; ++mt)
      for (int nt = 0; nt < 4; ++nt) s[mt][nt] = fzero;
    __builtin_amdgcn_s_setprio(1);
    for (int kk = 0; kk < 128; kk += 32) {
      bf16x8 bk4[4];
      for (int nt = 0; nt < 4; ++nt) bk4[nt] = *(const bf16x8*)&Ks[cur][swz128(nt * 16 + rowf, kk + kq8)];
      for (int mt = 0; mt < 2; ++mt)
        for (int nt = 0; nt < 4; ++nt)
          s[mt][nt] = MFMA16(qf[kk >> 5][mt], bk4[nt], s[mt][nt]);
    }
    __builtin_amdgcn_s_setprio(0);

    // softmax-lite: |s| <= 1, so p = exp(s) is unconditionally stable.
    for (int mt = 0; mt < 2; ++mt)
      for (int nt = 0; nt < 4; ++nt)
        for (int r = 0; r < 4; ++r) {
          float p = __expf(s[mt][nt][r]);
          lrow[mt][r] += p;
          int rr = wave * 32 + mt * 16 + ((lane >> 4) << 2) + r;
          int cc = nt * 16 + (lane & 15);
          Ps[swz64(rr, cc)] = (__bf16)p;
        }

    // O += P @ V   (P rows are own-wave only: intra-wave lgkmcnt ordering)
    __builtin_amdgcn_s_setprio(1);
    for (int kk = 0; kk < 64; kk += 32) {
      bf16x8 ap[2];
      for (int mt = 0; mt < 2; ++mt)
        ap[mt] = *(const bf16x8*)&Ps[swz64(wave * 32 + mt * 16 + rowf, kk + kq8)];
      for (int nt = 0; nt < 8; ++nt) {
        bf16x8 bvv = *(const bf16x8*)&Vts[cur][swz64(nt * 16 + rowf, kk + kq8)];
        for (int mt = 0; mt < 2; ++mt)
          o[mt][nt] = MFMA16(ap[mt], bvv, o[mt][nt]);
      }
    }
    __builtin_amdgcn_s_setprio(0);

    __syncthreads();   // drains next-tile stage (flew over compute) + guards swap
    cur ^= 1;
  }
#undef STAGE_KV

  // epilogue: single denom reduce, divide, write fp32 out [B][L][H][HD]
  const int b = bh >> 4, h = bh & 15;
  for (int mt = 0; mt < 2; ++mt) {
    for (int r = 0; r < 4; ++r) {
      float lsum = lrow[mt][r];
      for (int off = 8; off; off >>= 1) lsum += __shfl_xor(lsum, off);
      float inv = 1.0f / lsum;
      int l = q0 + wave * 32 + mt * 16 + ((lane >> 4) << 2) + r;
      float* op = out + (((size_t)b * L_ + l) * H_ + h) * HD_;
      for (int nt = 0; nt < 8; ++nt) {
        int d = nt * 16 + (lane & 15);
        op[d] = o[mt][nt][r] * inv;
      }
    }
  }
}

// ---------------------------------------------------------------------------
extern "C" void kernel_launch(void* const* d_in, const int* in_sizes, int n_in,
                              void* d_out, int out_size, void* d_ws, size_t ws_size,
                              hipStream_t stream)
{
  const float* X    = (const float*)d_in[0];   // [4,2048,2048] fp32
  const float* W    = (const float*)d_in[1];   // [6144,2048] fp32
  const float* bias = (const float*)d_in[2];   // [6144] fp32
  float* out = (float*)d_out;                  // [4,2048,2048] fp32

  // bf16 copies of X and W live inside d_out (58.7MB < 67.1MB); d_out is not
  // written by anything until attn, which runs after gemm_qkv has consumed them.
  bf16_t* Xb = (bf16_t*)d_out;
  bf16_t* Wb = Xb + NX;

  bf16_t* q  = (bf16_t*)d_ws;                  // [B,H,L,HD] 32MB (L2-normalized)
  bf16_t* k  = q + QK_ELEMS;                   // 32MB (L2-normalized)
  bf16_t* vT = k + QK_ELEMS;                   // [B,H,HD,L] 32MB

  cvt<<<dim3((NX + NW) / (256 * 4)), 256, 0, stream>>>(X, W, Xb);
  gemm_qkv<<<dim3(24, 32), 512, 0, stream>>>(Xb, Wb, bias, q, k, vT);
  attn<<<dim3(16, 64), 256, 0, stream>>>(q, k, vT, out);
}